// Round 14
// baseline (517.031 us; speedup 1.0000x reference)
//
#include <hip/hip_runtime.h>
#include <hip/hip_bf16.h>
#include <stdint.h>

#define SEQ     4096
#define NBATCH  16
#define DMODEL  768
#define NHEAD   12
#define HDIM    64
#define WINSZ   64
#define SHIFT_T 32
#define QKV_N   (3*DMODEL)   // 2304

typedef __attribute__((ext_vector_type(8)))  short bf16x8;
typedef __attribute__((ext_vector_type(4)))  float f32x4;

static __device__ __forceinline__ unsigned short f2bf(float f) {
  union { float f; unsigned u; } v; v.f = f;
  unsigned r = v.u + 0x7fffu + ((v.u >> 16) & 1u);
  return (unsigned short)(r >> 16);
}

#define G2L(gp, lp) __builtin_amdgcn_global_load_lds( \
    (const __attribute__((address_space(1))) unsigned*)(const void*)(gp), \
    (__attribute__((address_space(3))) unsigned*)(void*)(lp), 16, 0, 0)

#define MFMA16(a,b,c) __builtin_amdgcn_mfma_f32_16x16x32_bf16(a,b,c,0,0,0)
#define LDS8(p) (*(const bf16x8*)(p))
#define BARR __builtin_amdgcn_s_barrier()
#define SBAR __builtin_amdgcn_sched_barrier(0)
#define LGK0 do { asm volatile("s_waitcnt lgkmcnt(0)" ::: "memory"); SBAR; } while(0)

// ---- cast x (fp32) -> bf16 with +SHIFT roll fused
__global__ void k_cvt_x(const float* __restrict__ x, unsigned short* __restrict__ xb,
                        long long n8) {
  for (long long i = (long long)blockIdx.x*blockDim.x + threadIdx.x; i < n8;
       i += (long long)gridDim.x*blockDim.x) {
    long long e = i*8;
    int d = (int)(e % DMODEL);
    long long gt = e / DMODEL;
    int t = (int)(gt & (SEQ-1));
    long long b = gt >> 12;
    int ts = (t - SHIFT_T) & (SEQ-1);
    const float* src = x + (((b << 12) + ts) * (long long)DMODEL + d);
    float4 a0 = *(const float4*)src;
    float4 a1 = *(const float4*)(src + 4);
    bf16x8 o;
    o[0]=(short)f2bf(a0.x); o[1]=(short)f2bf(a0.y); o[2]=(short)f2bf(a0.z); o[3]=(short)f2bf(a0.w);
    o[4]=(short)f2bf(a1.x); o[5]=(short)f2bf(a1.y); o[6]=(short)f2bf(a1.z); o[7]=(short)f2bf(a1.w);
    *(bf16x8*)(xb + e) = o;
  }
}

__global__ void k_cvt_w(const float* __restrict__ w, unsigned short* __restrict__ wb, int n8) {
  int i = blockIdx.x*blockDim.x + threadIdx.x;
  if (i >= n8) return;
  float4 a0 = ((const float4*)w)[2*i];
  float4 a1 = ((const float4*)w)[2*i+1];
  bf16x8 o;
  o[0]=(short)f2bf(a0.x); o[1]=(short)f2bf(a0.y); o[2]=(short)f2bf(a0.z); o[3]=(short)f2bf(a0.w);
  o[4]=(short)f2bf(a1.x); o[5]=(short)f2bf(a1.y); o[6]=(short)f2bf(a1.z); o[7]=(short)f2bf(a1.w);
  ((bf16x8*)wb)[i] = o;
}

// ---- QKV GEMM: 128x256 tile, BK=32, 3-slot LDS ring (72KB), 2 blocks/CU.
// ONE barrier + one counted vmcnt per K32-tile (16 MFMA). Stage 2 tiles
// ahead; steady-state wait = vmcnt(3).
// Read offsets: FULL-offset XOR (r2-validated). 64B rows put the row-parity
// bit inside the key's span — XOR must cover cl*64, not just the chunk
// (r13's bug: chunk-only XOR double-counted bit 6 for cl>=8 -> wrong rows).
// Output: head-grouped panels [w][h][t][64r][64c] for attn.
__global__ __launch_bounds__(512, 4)
void k_qkv128(const unsigned short* __restrict__ A, const unsigned short* __restrict__ Bw,
              const float* __restrict__ bias, unsigned short* __restrict__ Cb) {
  __shared__ char lds[3*24576];               // 3 ring slots x (A 8KB + B 16KB)
  const int nTN = QKV_N/256;                  // 9
  int nwg = gridDim.x;
  int cpx = nwg >> 3;
  int wg  = (blockIdx.x & 7) * cpx + (blockIdx.x >> 3);   // XCD-contiguous
  int bm = wg / nTN, bn = wg - bm*nTN;
  long long m0 = (long long)bm * 128;
  int n0 = bn * 256;
  int tid = threadIdx.x;
  int lane = tid & 63, wid = tid >> 6;
  int wr = wid >> 2, wc = wid & 3;            // 2M x 4N waves, 64x64 of C each
  int cl = lane & 15, g4 = lane >> 4;

  const long long K2 = 2LL * DMODEL;
  int L  = tid * 16;
  int Ls = L ^ (((L >> 7) & 7) << 4);         // involution (r2-validated)
  int srow = Ls >> 6, scol = Ls & 63;         // 128 rows x 64B per 8KB block
  const char* gA  = (const char*)A  + (m0 + srow) * K2 + scol;
  const char* gB0 = (const char*)Bw + (long long)(n0 +       srow) * K2 + scol;
  const char* gB1 = (const char*)Bw + (long long)(n0 + 128 + srow) * K2 + scol;

  int key  = (cl >> 1) << 4;
  int aoff = (wr*4096 + cl*64 + g4*16) ^ key;            // + mf*1024 (XOR-safe)
  int boff = 8192 + ((wc*4096 + cl*64 + g4*16) ^ key);   // + nf*1024 (XOR-safe)

  f32x4 acc[4][4];
  #pragma unroll
  for (int i = 0; i < 4; ++i)
    #pragma unroll
    for (int j = 0; j < 4; ++j) acc[i][j] = (f32x4){0.f,0.f,0.f,0.f};

  // prologue: stage tiles 0 (slot0) and 1 (slot1); drain tile 0, keep tile 1
  G2L(gA,       lds + L);
  G2L(gB0,      lds + 8192  + L);
  G2L(gB1,      lds + 16384 + L);
  G2L(gA  + 64, lds + 24576 + L);
  G2L(gB0 + 64, lds + 24576 + 8192  + L);
  G2L(gB1 + 64, lds + 24576 + 16384 + L);
  gA += 128; gB0 += 128; gB1 += 128;          // now point at tile 2
  asm volatile("s_waitcnt vmcnt(3)" ::: "memory");
  SBAR; BARR;

  // one K32-tile: {stage t+2 | 8 ds_reads | lgkm0 | 16 MFMA | vmcnt | BARR}
#define QT(RS, SS, DOSTAGE, WSTR) do {                                        \
    const char* rb = lds + (RS)*24576;                                        \
    char* sb = lds + (SS)*24576;                                              \
    if (DOSTAGE) { G2L(gA, sb + L); G2L(gB0, sb + 8192 + L);                  \
                   G2L(gB1, sb + 16384 + L);                                  \
                   gA += 64; gB0 += 64; gB1 += 64; }                          \
    bf16x8 a0 = LDS8(rb + aoff);        bf16x8 a1 = LDS8(rb + aoff + 1024);   \
    bf16x8 a2 = LDS8(rb + aoff + 2048); bf16x8 a3 = LDS8(rb + aoff + 3072);   \
    bf16x8 b0 = LDS8(rb + boff);        bf16x8 b1 = LDS8(rb + boff + 1024);   \
    bf16x8 b2 = LDS8(rb + boff + 2048); bf16x8 b3 = LDS8(rb + boff + 3072);   \
    LGK0;                                                                     \
    __builtin_amdgcn_s_setprio(1);                                            \
    acc[0][0]=MFMA16(a0,b0,acc[0][0]); acc[0][1]=MFMA16(a0,b1,acc[0][1]);     \
    acc[0][2]=MFMA16(a0,b2,acc[0][2]); acc[0][3]=MFMA16(a0,b3,acc[0][3]);     \
    acc[1][0]=MFMA16(a1,b0,acc[1][0]); acc[1][1]=MFMA16(a1,b1,acc[1][1]);     \
    acc[1][2]=MFMA16(a1,b2,acc[1][2]); acc[1][3]=MFMA16(a1,b3,acc[1][3]);     \
    acc[2][0]=MFMA16(a2,b0,acc[2][0]); acc[2][1]=MFMA16(a2,b1,acc[2][1]);     \
    acc[2][2]=MFMA16(a2,b2,acc[2][2]); acc[2][3]=MFMA16(a2,b3,acc[2][3]);     \
    acc[3][0]=MFMA16(a3,b0,acc[3][0]); acc[3][1]=MFMA16(a3,b1,acc[3][1]);     \
    acc[3][2]=MFMA16(a3,b2,acc[3][2]); acc[3][3]=MFMA16(a3,b3,acc[3][3]);     \
    __builtin_amdgcn_s_setprio(0); SBAR;                                      \
    asm volatile(WSTR ::: "memory"); SBAR;                                    \
    BARR;                                                                     \
  } while (0)

  // 24 K32-tiles: 7 x {0,1,2}, then peeled 21,22,23
  for (int i = 0; i < 7; ++i) {
    QT(0, 2, 1, "s_waitcnt vmcnt(3)");
    QT(1, 0, 1, "s_waitcnt vmcnt(3)");
    QT(2, 1, 1, "s_waitcnt vmcnt(3)");
  }
  QT(0, 2, 1, "s_waitcnt vmcnt(3)");   // t=21, stages t=23
  QT(1, 0, 0, "s_waitcnt vmcnt(0)");   // t=22, drain t=23
  QT(2, 1, 0, "");                     // t=23
#undef QT

  // ---- epilogue: head-grouped panels [w][h][t][64r][64c]
  #pragma unroll
  for (int mf = 0; mf < 4; ++mf) {
    #pragma unroll
    for (int nf = 0; nf < 4; ++nf) {
      int n = n0 + wc*64 + nf*16 + cl;
      float bv = bias[n];
      int nb = n0 + wc*64;
      int t  = nb / DMODEL;
      int h  = (nb - t*DMODEL) >> 6;
      #pragma unroll
      for (int r = 0; r < 4; ++r) {
        long long m = m0 + wr*64 + mf*16 + g4*4 + r;
        long long panel = ((((m >> 6)*NHEAD + h)*3 + t) << 12);
        Cb[panel + ((m & 63) << 6) + nf*16 + cl] = f2bf(acc[mf][nf][r] + bv);
      }
    }
  }
}

// ---- 256x256 bf16 GEMM (round-5 verbatim): proj only (MODE 1).
template<int MODE>
__global__ __launch_bounds__(512, 1)
void k_gemm256(const unsigned short* __restrict__ A, const unsigned short* __restrict__ Bw,
               const float* __restrict__ bias, unsigned short* __restrict__ Cb,
               float* __restrict__ Cf, int M, int N, int K, int nTN, long long c0) {
  __shared__ char lds[131072];
  const int nt = K >> 6;
  int nwg = gridDim.x;
  int cpx = nwg >> 3;
  int wg  = (blockIdx.x & 7) * cpx + (blockIdx.x >> 3);
  int bm = wg / nTN, bn = wg - bm*nTN;
  long long m0 = (long long)bm * 256;
  int n0 = bn * 256;
  int tid = threadIdx.x;
  int lane = tid & 63, wid = tid >> 6;
  int wr = wid >> 2, wc = wid & 3;
  int cl = lane & 15, g4 = lane >> 4;

  const long long K2 = 2LL * K;
  int L  = tid * 16;
  int Ls = L ^ (((L >> 7) & 7) << 4);
  int srow = Ls >> 7, scol = Ls & 127;
  const char* gAr0 = (const char*)A + (m0 +       srow) * K2 + scol;
  const char* gAr1 = (const char*)A + (m0 +  64 + srow) * K2 + scol;
  const char* gAr2 = (const char*)A + (m0 + 128 + srow) * K2 + scol;
  const char* gAr3 = (const char*)A + (m0 + 192 + srow) * K2 + scol;
  const char* gBr0 = (const char*)Bw + (long long)(n0 +       srow) * K2 + scol;
  const char* gBr1 = (const char*)Bw + (long long)(n0 +  64 + srow) * K2 + scol;
  const char* gBr2 = (const char*)Bw + (long long)(n0 + 128 + srow) * K2 + scol;
  const char* gBr3 = (const char*)Bw + (long long)(n0 + 192 + srow) * K2 + scol;

  int p0 = cl*128 + ((g4*16) ^ ((cl & 7) << 4));
  int p1 = p0 ^ 64;
  int RA0 = wr*16384;
  int RA1 = wr*16384 + 8192;
  int BB  = 32768 + wc*8192;

  f32x4 acc[8][4];
  #pragma unroll
  for (int i = 0; i < 8; ++i)
    #pragma unroll
    for (int j = 0; j < 4; ++j) acc[i][j] = (f32x4){0.f,0.f,0.f,0.f};

#define MMPH(MA, MB, x0, x1, y0, y1) \
  acc[MA][0]=MFMA16(x0,b00,acc[MA][0]); acc[MA][1]=MFMA16(x0,b10,acc[MA][1]); \
  acc[MA][2]=MFMA16(x0,b20,acc[MA][2]); acc[MA][3]=MFMA16(x0,b30,acc[MA][3]); \
  acc[MB][0]=MFMA16(y0,b00,acc[MB][0]); acc[MB][1]=MFMA16(y0,b10,acc[MB][1]); \
  acc[MB][2]=MFMA16(y0,b20,acc[MB][2]); acc[MB][3]=MFMA16(y0,b30,acc[MB][3]); \
  acc[MA][0]=MFMA16(x1,b01,acc[MA][0]); acc[MA][1]=MFMA16(x1,b11,acc[MA][1]); \
  acc[MA][2]=MFMA16(x1,b21,acc[MA][2]); acc[MA][3]=MFMA16(x1,b31,acc[MA][3]); \
  acc[MB][0]=MFMA16(y1,b01,acc[MB][0]); acc[MB][1]=MFMA16(y1,b11,acc[MB][1]); \
  acc[MB][2]=MFMA16(y1,b21,acc[MB][2]); acc[MB][3]=MFMA16(y1,b31,acc[MB][3]);

#define TILE(RD, ST, DOSTAGE, WBSTR, DOWA) do {                               \
    const char* rbuf = (RD); char* stb = (ST);                                \
    bf16x8 b00,b01,b10,b11,b20,b21,b30,b31;                                   \
    { bf16x8 x0 = LDS8(rbuf + RA0        + p0), x1 = LDS8(rbuf + RA0        + p1);\
      bf16x8 y0 = LDS8(rbuf + RA0 + 2048 + p0), y1 = LDS8(rbuf + RA0 + 2048 + p1);\
      b00 = LDS8(rbuf + BB        + p0);  b01 = LDS8(rbuf + BB        + p1);  \
      b10 = LDS8(rbuf + BB + 2048 + p0);  b11 = LDS8(rbuf + BB + 2048 + p1);  \
      b20 = LDS8(rbuf + BB + 4096 + p0);  b21 = LDS8(rbuf + BB + 4096 + p1);  \
      b30 = LDS8(rbuf + BB + 6144 + p0);  b31 = LDS8(rbuf + BB + 6144 + p1);  \
      if (DOSTAGE) { G2L(gBr0, stb + 32768 + L); G2L(gBr1, stb + 40960 + L); }\
      asm volatile("s_waitcnt lgkmcnt(8)" ::: "memory"); SBAR;                \
      BARR; LGK0;                                                             \
      __builtin_amdgcn_s_setprio(1);                                          \
      MMPH(0, 1, x0, x1, y0, y1)                                              \
      __builtin_amdgcn_s_setprio(0); SBAR; BARR;                              \
    }                                                                         \
    { bf16x8 x0 = LDS8(rbuf + RA0 + 4096 + p0), x1 = LDS8(rbuf + RA0 + 4096 + p1);\
      bf16x8 y0 = LDS8(rbuf + RA0 + 6144 + p0), y1 = LDS8(rbuf + RA0 + 6144 + p1);\
      if (DOSTAGE) { G2L(gBr2, stb + 49152 + L); G2L(gBr3, stb + 57344 + L); }\
      SBAR; BARR; LGK0;                                                       \
      __builtin_amdgcn_s_setprio(1);                                          \
      MMPH(2, 3, x0, x1, y0, y1)                                              \
      __builtin_amdgcn_s_setprio(0); SBAR;                                    \
      asm volatile(WBSTR ::: "memory"); SBAR; BARR;                           \
    }                                                                         \
    { bf16x8 x0 = LDS8(rbuf + RA1        + p0), x1 = LDS8(rbuf + RA1        + p1);\
      bf16x8 y0 = LDS8(rbuf + RA1 + 2048 + p0), y1 = LDS8(rbuf + RA1 + 2048 + p1);\
      if (DOSTAGE) { G2L(gAr0, stb + L); G2L(gAr2, stb + 16384 + L); }        \
      SBAR; BARR; LGK0;                                                       \
      __builtin_amdgcn_s_setprio(1);                                          \
      MMPH(4, 5, x0, x1, y0, y1)                                              \
      __builtin_amdgcn_s_setprio(0); SBAR; BARR;                              \
    }                                                                         \
    { bf16x8 x0 = LDS8(rbuf + RA1 + 4096 + p0), x1 = LDS8(rbuf + RA1 + 4096 + p1);\
      bf16x8 y0 = LDS8(rbuf + RA1 + 6144 + p0), y1 = LDS8(rbuf + RA1 + 6144 + p1);\
      if (DOSTAGE) { G2L(gAr1, stb + 8192 + L); G2L(gAr3, stb + 24576 + L);   \
                     gAr0 += 128; gAr1 += 128; gAr2 += 128; gAr3 += 128;      \
                     gBr0 += 128; gBr1 += 128; gBr2 += 128; gBr3 += 128; }    \
      SBAR; BARR; LGK0;                                                       \
      __builtin_amdgcn_s_setprio(1);                                          \
      MMPH(6, 7, x0, x1, y0, y1)                                              \
      __builtin_amdgcn_s_setprio(0); SBAR;                                    \
      if (DOWA) { asm volatile("s_waitcnt vmcnt(2)" ::: "memory"); }          \
      SBAR; BARR;                                                             \
    }                                                                         \
  } while (0)

  G2L(gBr0, lds + 32768 + L); G2L(gBr1, lds + 40960 + L);
  G2L(gBr2, lds + 49152 + L); G2L(gBr3, lds + 57344 + L);
  G2L(gAr0, lds + L);         G2L(gAr2, lds + 16384 + L);
  G2L(gAr1, lds + 8192 + L);  G2L(gAr3, lds + 24576 + L);
  gAr0 += 128; gAr1 += 128; gAr2 += 128; gAr3 += 128;
  gBr0 += 128; gBr1 += 128; gBr2 += 128; gBr3 += 128;
  asm volatile("s_waitcnt vmcnt(2)" ::: "memory");
  SBAR; BARR;

  char* const bufA = lds;
  char* const bufB = lds + 65536;
  for (int i = 0; i < (nt - 2) / 2; ++i) {
    TILE(bufA, bufB, 1, "s_waitcnt vmcnt(4)", 1);
    TILE(bufB, bufA, 1, "s_waitcnt vmcnt(4)", 1);
  }
  TILE(bufA, bufB, 1, "s_waitcnt vmcnt(4)", 1);
  TILE(bufB, bufA, 0, "s_waitcnt vmcnt(0)", 0);
#undef TILE
#undef MMPH

  #pragma unroll
  for (int mf = 0; mf < 8; ++mf) {
    #pragma unroll
    for (int nf = 0; nf < 4; ++nf) {
      int n = n0 + wc*64 + nf*16 + cl;
      float bv = bias[n];
      #pragma unroll
      for (int r = 0; r < 4; ++r) {
        long long m = m0 + wr*128 + mf*16 + g4*4 + r;
        float v = acc[mf][nf][r] + bv;
        if (MODE == 0) {
          Cb[m * (long long)N + n] = f2bf(v);
        } else {
          long long gm = c0 + m;
          long long om = (gm & ~(long long)(SEQ-1)) | ((gm - SHIFT_T) & (long long)(SEQ-1));
          Cf[om * (long long)N + n] = v;
        }
      }
    }
  }
}

// ---- per-(window,head) attention; reads head-grouped qkv (24KB contiguous)
__global__ __launch_bounds__(256, 4)
void k_attn(const unsigned short* __restrict__ qkv, const float* __restrict__ rel_bias,
            unsigned short* __restrict__ y) {
  int w = blockIdx.x / NHEAD;
  int h = blockIdx.x - w*NHEAD;
  __shared__ unsigned short sQ[64*72], sK[64*72], sV[64*72];
  __shared__ unsigned short sP[4][16*72];
  __shared__ float rb[128];
  int tid = threadIdx.x, lane = tid & 63, wid = tid >> 6;
  int cl = lane & 15, g4 = lane >> 4;

  if (tid < 2*WINSZ - 1) rb[tid] = rel_bias[h*(2*WINSZ-1) + tid];

  const unsigned short* panel = qkv + ((long long)((w*NHEAD + h)*3) << 12);
  {
    int row = tid >> 2, c16 = (tid & 3) * 16;
    const unsigned short* s0 = panel + tid*16;
    *(bf16x8*)(sQ + row*72 + c16)     = *(const bf16x8*)(s0);
    *(bf16x8*)(sQ + row*72 + c16 + 8) = *(const bf16x8*)(s0 + 8);
    *(bf16x8*)(sK + row*72 + c16)     = *(const bf16x8*)(s0 + 4096);
    *(bf16x8*)(sK + row*72 + c16 + 8) = *(const bf16x8*)(s0 + 4096 + 8);
    *(bf16x8*)(sV + row*72 + c16)     = *(const bf16x8*)(s0 + 8192);
    *(bf16x8*)(sV + row*72 + c16 + 8) = *(const bf16x8*)(s0 + 8192 + 8);
  }
  __syncthreads();

  f32x4 sc[4];
  #pragma unroll
  for (int nt = 0; nt < 4; ++nt) sc[nt] = (f32x4){0.f,0.f,0.f,0.f};
  #pragma unroll
  for (int kk = 0; kk < 2; ++kk) {
    bf16x8 aq = *(const bf16x8*)(sQ + (wid*16 + cl)*72 + kk*32 + g4*8);
    #pragma unroll
    for (int nt = 0; nt < 4; ++nt) {
      bf16x8 bk = *(const bf16x8*)(sK + (nt*16 + cl)*72 + kk*32 + g4*8);
      sc[nt] = MFMA16(aq, bk, sc[nt]);
    }
  }

  float pv[4][4];
  #pragma unroll
  for (int r = 0; r < 4; ++r) {
    int qi = wid*16 + g4*4 + r;
    float mx = -1e30f;
    #pragma unroll
    for (int nt = 0; nt < 4; ++nt) {
      int kj = nt*16 + cl;
      float v = sc[nt][r]*0.125f + rb[kj - qi + (WINSZ-1)];
      pv[nt][r] = v;
      mx = fmaxf(mx, v);
    }
    #pragma unroll
    for (int m = 1; m < 16; m <<= 1) mx = fmaxf(mx, __shfl_xor(mx, m, 64));
    float sum = 0.f;
    #pragma unroll
    for (int nt = 0; nt < 4; ++nt) { float e = __expf(pv[nt][r]-mx); pv[nt][r] = e; sum += e; }
    #pragma unroll
    for (int m = 1; m < 16; m <<= 1) sum += __shfl_xor(sum, m, 64);
    float inv = 1.f / sum;
    #pragma unroll
    for (int nt = 0; nt < 4; ++nt)
      sP[wid][(g4*4+r)*72 + nt*16 + cl] = f2bf(pv[nt][r]*inv);
  }

  f32x4 o[4];
  #pragma unroll
  for (int nt = 0; nt < 4; ++nt) o[nt] = (f32x4){0.f,0.f,0.f,0.f};
  #pragma unroll
  for (int kk = 0; kk < 2; ++kk) {
    bf16x8 ap = *(const bf16x8*)(&sP[wid][cl*72 + kk*32 + g4*8]);
    #pragma unroll
    for (int nt = 0; nt < 4; ++nt) {
      bf16x8 bv;
      #pragma unroll
      for (int j = 0; j < 8; ++j)
        bv[j] = (short)sV[(kk*32 + g4*8 + j)*72 + nt*16 + cl];
      o[nt] = MFMA16(ap, bv, o[nt]);
    }
  }

  long long tokbase = (long long)w * WINSZ;
  #pragma unroll
  for (int nt = 0; nt < 4; ++nt)
    #pragma unroll
    for (int r = 0; r < 4; ++r) {
      int row = wid*16 + g4*4 + r;
      y[(tokbase + row) * (long long)DMODEL + h*HDIM + nt*16 + cl] = f2bf(o[nt][r]);
    }
}

extern "C" void kernel_launch(void* const* d_in, const int* in_sizes, int n_in,
                              void* d_out, int out_size, void* d_ws, size_t ws_size,
                              hipStream_t stream) {
  const float* x      = (const float*)d_in[0];
  const float* qkv_w  = (const float*)d_in[1];
  const float* qkv_b  = (const float*)d_in[2];
  const float* proj_w = (const float*)d_in[3];
  const float* proj_b = (const float*)d_in[4];
  const float* rel_b  = (const float*)d_in[5];
  float* out = (float*)d_out;

  const long long NTOK = (long long)NBATCH * SEQ;    // 65536

  char* ws = (char*)d_ws;
  unsigned short* qkvb = (unsigned short*)ws;                               // 302 MB head-grouped
  unsigned short* yb   = (unsigned short*)(ws + (size_t)NTOK*QKV_N*2);      // 100.7 MB (xb in, y out)
  unsigned short* wq   = (unsigned short*)(ws + (size_t)NTOK*QKV_N*2 + (size_t)NTOK*DMODEL*2);
  unsigned short* wp   = wq + (size_t)QKV_N*DMODEL;

  k_cvt_w<<<(QKV_N*DMODEL/8 + 255)/256, 256, 0, stream>>>(qkv_w, wq, QKV_N*DMODEL/8);
  k_cvt_w<<<(DMODEL*DMODEL/8 + 255)/256, 256, 0, stream>>>(proj_w, wp, DMODEL*DMODEL/8);

  long long n8 = NTOK * DMODEL / 8;
  k_cvt_x<<<2048, 256, 0, stream>>>(x, yb /*as xb*/, n8);

  // QKV: 512 M-tiles x 9 N-tiles = 4608 wgs; 2 blocks/CU -> 9.0 exact rounds
  k_qkv128<<<4608, 512, 0, stream>>>(yb, wq, qkv_b, qkvb);

  k_attn<<<(int)(NTOK/WINSZ) * NHEAD, 256, 0, stream>>>(qkvb, rel_b, yb /*reuse as y*/);

  int mT = (int)(NTOK / 256);                        // proj: 768 wgs = 3.0 rounds
  k_gemm256<1><<<mT * (DMODEL/256), 512, 0, stream>>>(yb, wp, proj_b, nullptr, out,
                                                      (int)NTOK, DMODEL, DMODEL, DMODEL/256, 0);
}

// Round 15
// 497.396 us; speedup vs baseline: 1.0395x; 1.0395x over previous
//
#include <hip/hip_runtime.h>
#include <hip/hip_bf16.h>
#include <stdint.h>

#define SEQ     4096
#define NBATCH  16
#define DMODEL  768
#define NHEAD   12
#define HDIM    64
#define WINSZ   64
#define SHIFT_T 32
#define QKV_N   (3*DMODEL)   // 2304

typedef __attribute__((ext_vector_type(8)))  short bf16x8;
typedef __attribute__((ext_vector_type(4)))  float f32x4;

static __device__ __forceinline__ unsigned short f2bf(float f) {
  union { float f; unsigned u; } v; v.f = f;
  unsigned r = v.u + 0x7fffu + ((v.u >> 16) & 1u);
  return (unsigned short)(r >> 16);
}

#define G2L(gp, lp) __builtin_amdgcn_global_load_lds( \
    (const __attribute__((address_space(1))) unsigned*)(const void*)(gp), \
    (__attribute__((address_space(3))) unsigned*)(void*)(lp), 16, 0, 0)

#define MFMA16(a,b,c) __builtin_amdgcn_mfma_f32_16x16x32_bf16(a,b,c,0,0,0)
#define LDS8(p) (*(const bf16x8*)(p))
#define BARR __builtin_amdgcn_s_barrier()
#define SBAR __builtin_amdgcn_sched_barrier(0)
#define LGK0 do { asm volatile("s_waitcnt lgkmcnt(0)" ::: "memory"); SBAR; } while(0)

// ---- cast x (fp32) -> bf16 with +SHIFT roll fused
__global__ void k_cvt_x(const float* __restrict__ x, unsigned short* __restrict__ xb,
                        long long n8) {
  for (long long i = (long long)blockIdx.x*blockDim.x + threadIdx.x; i < n8;
       i += (long long)gridDim.x*blockDim.x) {
    long long e = i*8;
    int d = (int)(e % DMODEL);
    long long gt = e / DMODEL;
    int t = (int)(gt & (SEQ-1));
    long long b = gt >> 12;
    int ts = (t - SHIFT_T) & (SEQ-1);
    const float* src = x + (((b << 12) + ts) * (long long)DMODEL + d);
    float4 a0 = *(const float4*)src;
    float4 a1 = *(const float4*)(src + 4);
    bf16x8 o;
    o[0]=(short)f2bf(a0.x); o[1]=(short)f2bf(a0.y); o[2]=(short)f2bf(a0.z); o[3]=(short)f2bf(a0.w);
    o[4]=(short)f2bf(a1.x); o[5]=(short)f2bf(a1.y); o[6]=(short)f2bf(a1.z); o[7]=(short)f2bf(a1.w);
    *(bf16x8*)(xb + e) = o;
  }
}

__global__ void k_cvt_w(const float* __restrict__ w, unsigned short* __restrict__ wb, int n8) {
  int i = blockIdx.x*blockDim.x + threadIdx.x;
  if (i >= n8) return;
  float4 a0 = ((const float4*)w)[2*i];
  float4 a1 = ((const float4*)w)[2*i+1];
  bf16x8 o;
  o[0]=(short)f2bf(a0.x); o[1]=(short)f2bf(a0.y); o[2]=(short)f2bf(a0.z); o[3]=(short)f2bf(a0.w);
  o[4]=(short)f2bf(a1.x); o[5]=(short)f2bf(a1.y); o[6]=(short)f2bf(a1.z); o[7]=(short)f2bf(a1.w);
  ((bf16x8*)wb)[i] = o;
}

// ---- 256x256 bf16 GEMM (round-5 K-loop verbatim).
// MODE 0: bf16 out, HEAD-GROUPED layout [w][h][t][64r][64c] (8KB panels) so
//         attn reads contiguous 24KB per (window,head).
// MODE 1: fp32 out with -SHIFT roll scatter.
template<int MODE>
__global__ __launch_bounds__(512, 1)
void k_gemm256(const unsigned short* __restrict__ A, const unsigned short* __restrict__ Bw,
               const float* __restrict__ bias, unsigned short* __restrict__ Cb,
               float* __restrict__ Cf, int M, int N, int K, int nTN, long long c0) {
  __shared__ char lds[131072];
  const int nt = K >> 6;
  int nwg = gridDim.x;
  int cpx = nwg >> 3;
  int wg  = (blockIdx.x & 7) * cpx + (blockIdx.x >> 3);
  int bm = wg / nTN, bn = wg - bm*nTN;
  long long m0 = (long long)bm * 256;
  int n0 = bn * 256;
  int tid = threadIdx.x;
  int lane = tid & 63, wid = tid >> 6;
  int wr = wid >> 2, wc = wid & 3;
  int cl = lane & 15, g4 = lane >> 4;

  const long long K2 = 2LL * K;
  int L  = tid * 16;
  int Ls = L ^ (((L >> 7) & 7) << 4);
  int srow = Ls >> 7, scol = Ls & 127;
  const char* gAr0 = (const char*)A + (m0 +       srow) * K2 + scol;
  const char* gAr1 = (const char*)A + (m0 +  64 + srow) * K2 + scol;
  const char* gAr2 = (const char*)A + (m0 + 128 + srow) * K2 + scol;
  const char* gAr3 = (const char*)A + (m0 + 192 + srow) * K2 + scol;
  const char* gBr0 = (const char*)Bw + (long long)(n0 +       srow) * K2 + scol;
  const char* gBr1 = (const char*)Bw + (long long)(n0 +  64 + srow) * K2 + scol;
  const char* gBr2 = (const char*)Bw + (long long)(n0 + 128 + srow) * K2 + scol;
  const char* gBr3 = (const char*)Bw + (long long)(n0 + 192 + srow) * K2 + scol;

  int p0 = cl*128 + ((g4*16) ^ ((cl & 7) << 4));
  int p1 = p0 ^ 64;
  int RA0 = wr*16384;
  int RA1 = wr*16384 + 8192;
  int BB  = 32768 + wc*8192;

  f32x4 acc[8][4];
  #pragma unroll
  for (int i = 0; i < 8; ++i)
    #pragma unroll
    for (int j = 0; j < 4; ++j) acc[i][j] = (f32x4){0.f,0.f,0.f,0.f};

#define MMPH(MA, MB, x0, x1, y0, y1) \
  acc[MA][0]=MFMA16(x0,b00,acc[MA][0]); acc[MA][1]=MFMA16(x0,b10,acc[MA][1]); \
  acc[MA][2]=MFMA16(x0,b20,acc[MA][2]); acc[MA][3]=MFMA16(x0,b30,acc[MA][3]); \
  acc[MB][0]=MFMA16(y0,b00,acc[MB][0]); acc[MB][1]=MFMA16(y0,b10,acc[MB][1]); \
  acc[MB][2]=MFMA16(y0,b20,acc[MB][2]); acc[MB][3]=MFMA16(y0,b30,acc[MB][3]); \
  acc[MA][0]=MFMA16(x1,b01,acc[MA][0]); acc[MA][1]=MFMA16(x1,b11,acc[MA][1]); \
  acc[MA][2]=MFMA16(x1,b21,acc[MA][2]); acc[MA][3]=MFMA16(x1,b31,acc[MA][3]); \
  acc[MB][0]=MFMA16(y1,b01,acc[MB][0]); acc[MB][1]=MFMA16(y1,b11,acc[MB][1]); \
  acc[MB][2]=MFMA16(y1,b21,acc[MB][2]); acc[MB][3]=MFMA16(y1,b31,acc[MB][3]);

#define TILE(RD, ST, DOSTAGE, WBSTR, DOWA) do {                               \
    const char* rbuf = (RD); char* stb = (ST);                                \
    bf16x8 b00,b01,b10,b11,b20,b21,b30,b31;                                   \
    { bf16x8 x0 = LDS8(rbuf + RA0        + p0), x1 = LDS8(rbuf + RA0        + p1);\
      bf16x8 y0 = LDS8(rbuf + RA0 + 2048 + p0), y1 = LDS8(rbuf + RA0 + 2048 + p1);\
      b00 = LDS8(rbuf + BB        + p0);  b01 = LDS8(rbuf + BB        + p1);  \
      b10 = LDS8(rbuf + BB + 2048 + p0);  b11 = LDS8(rbuf + BB + 2048 + p1);  \
      b20 = LDS8(rbuf + BB + 4096 + p0);  b21 = LDS8(rbuf + BB + 4096 + p1);  \
      b30 = LDS8(rbuf + BB + 6144 + p0);  b31 = LDS8(rbuf + BB + 6144 + p1);  \
      if (DOSTAGE) { G2L(gBr0, stb + 32768 + L); G2L(gBr1, stb + 40960 + L); }\
      asm volatile("s_waitcnt lgkmcnt(8)" ::: "memory"); SBAR;                \
      BARR; LGK0;                                                             \
      __builtin_amdgcn_s_setprio(1);                                          \
      MMPH(0, 1, x0, x1, y0, y1)                                              \
      __builtin_amdgcn_s_setprio(0); SBAR; BARR;                              \
    }                                                                         \
    { bf16x8 x0 = LDS8(rbuf + RA0 + 4096 + p0), x1 = LDS8(rbuf + RA0 + 4096 + p1);\
      bf16x8 y0 = LDS8(rbuf + RA0 + 6144 + p0), y1 = LDS8(rbuf + RA0 + 6144 + p1);\
      if (DOSTAGE) { G2L(gBr2, stb + 49152 + L); G2L(gBr3, stb + 57344 + L); }\
      SBAR; BARR; LGK0;                                                       \
      __builtin_amdgcn_s_setprio(1);                                          \
      MMPH(2, 3, x0, x1, y0, y1)                                              \
      __builtin_amdgcn_s_setprio(0); SBAR;                                    \
      asm volatile(WBSTR ::: "memory"); SBAR; BARR;                           \
    }                                                                         \
    { bf16x8 x0 = LDS8(rbuf + RA1        + p0), x1 = LDS8(rbuf + RA1        + p1);\
      bf16x8 y0 = LDS8(rbuf + RA1 + 2048 + p0), y1 = LDS8(rbuf + RA1 + 2048 + p1);\
      if (DOSTAGE) { G2L(gAr0, stb + L); G2L(gAr2, stb + 16384 + L); }        \
      SBAR; BARR; LGK0;                                                       \
      __builtin_amdgcn_s_setprio(1);                                          \
      MMPH(4, 5, x0, x1, y0, y1)                                              \
      __builtin_amdgcn_s_setprio(0); SBAR; BARR;                              \
    }                                                                         \
    { bf16x8 x0 = LDS8(rbuf + RA1 + 4096 + p0), x1 = LDS8(rbuf + RA1 + 4096 + p1);\
      bf16x8 y0 = LDS8(rbuf + RA1 + 6144 + p0), y1 = LDS8(rbuf + RA1 + 6144 + p1);\
      if (DOSTAGE) { G2L(gAr1, stb + 8192 + L); G2L(gAr3, stb + 24576 + L);   \
                     gAr0 += 128; gAr1 += 128; gAr2 += 128; gAr3 += 128;      \
                     gBr0 += 128; gBr1 += 128; gBr2 += 128; gBr3 += 128; }    \
      SBAR; BARR; LGK0;                                                       \
      __builtin_amdgcn_s_setprio(1);                                          \
      MMPH(6, 7, x0, x1, y0, y1)                                              \
      __builtin_amdgcn_s_setprio(0); SBAR;                                    \
      if (DOWA) { asm volatile("s_waitcnt vmcnt(2)" ::: "memory"); }          \
      SBAR; BARR;                                                             \
    }                                                                         \
  } while (0)

  G2L(gBr0, lds + 32768 + L); G2L(gBr1, lds + 40960 + L);
  G2L(gBr2, lds + 49152 + L); G2L(gBr3, lds + 57344 + L);
  G2L(gAr0, lds + L);         G2L(gAr2, lds + 16384 + L);
  G2L(gAr1, lds + 8192 + L);  G2L(gAr3, lds + 24576 + L);
  gAr0 += 128; gAr1 += 128; gAr2 += 128; gAr3 += 128;
  gBr0 += 128; gBr1 += 128; gBr2 += 128; gBr3 += 128;
  asm volatile("s_waitcnt vmcnt(2)" ::: "memory");
  SBAR; BARR;

  char* const bufA = lds;
  char* const bufB = lds + 65536;
  for (int i = 0; i < (nt - 2) / 2; ++i) {
    TILE(bufA, bufB, 1, "s_waitcnt vmcnt(4)", 1);
    TILE(bufB, bufA, 1, "s_waitcnt vmcnt(4)", 1);
  }
  TILE(bufA, bufB, 1, "s_waitcnt vmcnt(4)", 1);
  TILE(bufB, bufA, 0, "s_waitcnt vmcnt(0)", 0);
#undef TILE
#undef MMPH

  #pragma unroll
  for (int mf = 0; mf < 8; ++mf) {
    #pragma unroll
    for (int nf = 0; nf < 4; ++nf) {
      int n = n0 + wc*64 + nf*16 + cl;
      float bv = bias[n];
      #pragma unroll
      for (int r = 0; r < 4; ++r) {
        long long m = m0 + wr*128 + mf*16 + g4*4 + r;
        float v = acc[mf][nf][r] + bv;
        if (MODE == 0) {
          // head-grouped: [w][h][t][rr][c], 4096 u16 per (w,h,t) panel
          int nb = n0 + wc*64;                 // 64-aligned
          int t  = nb / DMODEL;                // 0..2 (q/k/v)
          int h  = (nb - t*DMODEL) >> 6;       // head
          long long panel = ((((m >> 6)*NHEAD + h)*3 + t) << 12);
          Cb[panel + ((m & 63) << 6) + nf*16 + cl] = f2bf(v);
        } else {
          long long gm = c0 + m;
          long long om = (gm & ~(long long)(SEQ-1)) | ((gm - SHIFT_T) & (long long)(SEQ-1));
          Cf[om * (long long)N + n] = v;
        }
      }
    }
  }
}

// ---- per-(window,head) attention; reads head-grouped qkv (24KB contiguous)
__global__ __launch_bounds__(256, 4)
void k_attn(const unsigned short* __restrict__ qkv, const float* __restrict__ rel_bias,
            unsigned short* __restrict__ y) {
  int w = blockIdx.x / NHEAD;
  int h = blockIdx.x - w*NHEAD;
  __shared__ unsigned short sQ[64*72], sK[64*72], sV[64*72];
  __shared__ unsigned short sP[4][16*72];
  __shared__ float rb[128];
  int tid = threadIdx.x, lane = tid & 63, wid = tid >> 6;
  int cl = lane & 15, g4 = lane >> 4;

  if (tid < 2*WINSZ - 1) rb[tid] = rel_bias[h*(2*WINSZ-1) + tid];

  // contiguous panels: [(w*12+h)*3 + t] * 4096 u16
  const unsigned short* panel = qkv + ((long long)((w*NHEAD + h)*3) << 12);
  {
    int row = tid >> 2, c16 = (tid & 3) * 16;
    const unsigned short* s0 = panel + tid*16;
    *(bf16x8*)(sQ + row*72 + c16)     = *(const bf16x8*)(s0);
    *(bf16x8*)(sQ + row*72 + c16 + 8) = *(const bf16x8*)(s0 + 8);
    *(bf16x8*)(sK + row*72 + c16)     = *(const bf16x8*)(s0 + 4096);
    *(bf16x8*)(sK + row*72 + c16 + 8) = *(const bf16x8*)(s0 + 4096 + 8);
    *(bf16x8*)(sV + row*72 + c16)     = *(const bf16x8*)(s0 + 8192);
    *(bf16x8*)(sV + row*72 + c16 + 8) = *(const bf16x8*)(s0 + 8192 + 8);
  }
  __syncthreads();

  f32x4 sc[4];
  #pragma unroll
  for (int nt = 0; nt < 4; ++nt) sc[nt] = (f32x4){0.f,0.f,0.f,0.f};
  #pragma unroll
  for (int kk = 0; kk < 2; ++kk) {
    bf16x8 aq = *(const bf16x8*)(sQ + (wid*16 + cl)*72 + kk*32 + g4*8);
    #pragma unroll
    for (int nt = 0; nt < 4; ++nt) {
      bf16x8 bk = *(const bf16x8*)(sK + (nt*16 + cl)*72 + kk*32 + g4*8);
      sc[nt] = MFMA16(aq, bk, sc[nt]);
    }
  }

  float pv[4][4];
  #pragma unroll
  for (int r = 0; r < 4; ++r) {
    int qi = wid*16 + g4*4 + r;
    float mx = -1e30f;
    #pragma unroll
    for (int nt = 0; nt < 4; ++nt) {
      int kj = nt*16 + cl;
      float v = sc[nt][r]*0.125f + rb[kj - qi + (WINSZ-1)];
      pv[nt][r] = v;
      mx = fmaxf(mx, v);
    }
    #pragma unroll
    for (int m = 1; m < 16; m <<= 1) mx = fmaxf(mx, __shfl_xor(mx, m, 64));
    float sum = 0.f;
    #pragma unroll
    for (int nt = 0; nt < 4; ++nt) { float e = __expf(pv[nt][r]-mx); pv[nt][r] = e; sum += e; }
    #pragma unroll
    for (int m = 1; m < 16; m <<= 1) sum += __shfl_xor(sum, m, 64);
    float inv = 1.f / sum;
    #pragma unroll
    for (int nt = 0; nt < 4; ++nt)
      sP[wid][(g4*4+r)*72 + nt*16 + cl] = f2bf(pv[nt][r]*inv);
  }

  f32x4 o[4];
  #pragma unroll
  for (int nt = 0; nt < 4; ++nt) o[nt] = (f32x4){0.f,0.f,0.f,0.f};
  #pragma unroll
  for (int kk = 0; kk < 2; ++kk) {
    bf16x8 ap = *(const bf16x8*)(&sP[wid][cl*72 + kk*32 + g4*8]);
    #pragma unroll
    for (int nt = 0; nt < 4; ++nt) {
      bf16x8 bv;
      #pragma unroll
      for (int j = 0; j < 8; ++j)
        bv[j] = (short)sV[(kk*32 + g4*8 + j)*72 + nt*16 + cl];
      o[nt] = MFMA16(ap, bv, o[nt]);
    }
  }

  long long tokbase = (long long)w * WINSZ;
  #pragma unroll
  for (int nt = 0; nt < 4; ++nt)
    #pragma unroll
    for (int r = 0; r < 4; ++r) {
      int row = wid*16 + g4*4 + r;
      y[(tokbase + row) * (long long)DMODEL + h*HDIM + nt*16 + cl] = f2bf(o[nt][r]);
    }
}

extern "C" void kernel_launch(void* const* d_in, const int* in_sizes, int n_in,
                              void* d_out, int out_size, void* d_ws, size_t ws_size,
                              hipStream_t stream) {
  const float* x      = (const float*)d_in[0];
  const float* qkv_w  = (const float*)d_in[1];
  const float* qkv_b  = (const float*)d_in[2];
  const float* proj_w = (const float*)d_in[3];
  const float* proj_b = (const float*)d_in[4];
  const float* rel_b  = (const float*)d_in[5];
  float* out = (float*)d_out;

  const long long NTOK = (long long)NBATCH * SEQ;    // 65536

  char* ws = (char*)d_ws;
  unsigned short* qkvb = (unsigned short*)ws;                               // 302 MB head-grouped
  unsigned short* yb   = (unsigned short*)(ws + (size_t)NTOK*QKV_N*2);      // 100.7 MB (xb in, y out)
  unsigned short* wq   = (unsigned short*)(ws + (size_t)NTOK*QKV_N*2 + (size_t)NTOK*DMODEL*2);
  unsigned short* wp   = wq + (size_t)QKV_N*DMODEL;

  k_cvt_w<<<(QKV_N*DMODEL/8 + 255)/256, 256, 0, stream>>>(qkv_w, wq, QKV_N*DMODEL/8);
  k_cvt_w<<<(DMODEL*DMODEL/8 + 255)/256, 256, 0, stream>>>(proj_w, wp, DMODEL*DMODEL/8);

  // full-run pipeline, no chunking: every GEMM grid is an exact CU-round count
  long long n8 = NTOK * DMODEL / 8;
  k_cvt_x<<<2048, 256, 0, stream>>>(x, yb /*as xb*/, n8);

  int mT = (int)(NTOK / 256);                        // 256 M-tiles
  k_gemm256<0><<<mT * (QKV_N/256), 512, 0, stream>>>(yb, wq, qkv_b, qkvb, nullptr,
                                                     (int)NTOK, QKV_N, DMODEL, QKV_N/256, 0);
  k_attn<<<(int)(NTOK/WINSZ) * NHEAD, 256, 0, stream>>>(qkvb, rel_b, yb /*reuse as y*/);
  k_gemm256<1><<<mT * (DMODEL/256), 512, 0, stream>>>(yb, wp, proj_b, nullptr, out,
                                                      (int)NTOK, DMODEL, DMODEL, DMODEL/256, 0);
}